// Round 9
// baseline (624.042 us; speedup 1.0000x reference)
//
#include <hip/hip_runtime.h>
#include <stdint.h>

// DotAtt: B=16, Lq=Lk=2048, D=64. scores = 64*Q.K^T ; softmax over q (axis=-2);
// JAX threefry dropout p=0.1 (key 42, partitionable); out = W.V
// Pass 1: column stats M[k], R[k]=1/(0.9*Z[k]).  Pass 2: O = (exp(s-M)*R*keep) . V
//
// Dropout draw (partitionable path, bit_width=32): bits = x0 ^ x1 of
// threefry2x32(key=(0,42), ctr=(0,j)) -- XOR of BOTH output words (prng.py).

#define LQ 2048
#define DD 64

__device__ __forceinline__ void tf_round(uint32_t& x0, uint32_t& x1, const int r) {
  x0 += x1;
  x1 = (x1 << r) | (x1 >> (32 - r));
  x1 ^= x0;
}

__device__ __forceinline__ bool keep_bit(uint32_t j) {
  const uint32_t ks1 = 42u, ks2 = 0x1BD11BDAu ^ 42u;
  uint32_t x0 = 0u;
  uint32_t x1 = j + ks1;
  tf_round(x0,x1,13); tf_round(x0,x1,15); tf_round(x0,x1,26); tf_round(x0,x1,6);
  x0 += ks1; x1 += ks2 + 1u;
  tf_round(x0,x1,17); tf_round(x0,x1,29); tf_round(x0,x1,16); tf_round(x0,x1,24);
  x0 += ks2; x1 += 0u + 2u;
  tf_round(x0,x1,13); tf_round(x0,x1,15); tf_round(x0,x1,26); tf_round(x0,x1,6);
  x0 += 0u; x1 += ks1 + 3u;
  tf_round(x0,x1,17); tf_round(x0,x1,29); tf_round(x0,x1,16); tf_round(x0,x1,24);
  x0 += ks1; x1 += ks2 + 4u;
  tf_round(x0,x1,13); tf_round(x0,x1,15); tf_round(x0,x1,26); tf_round(x0,x1,6);
  x0 += ks2; x1 += 0u + 5u;
  uint32_t bits = x0 ^ x1;            // partitionable 32-bit draw: XOR both words
  float u = __uint_as_float((bits >> 9) | 0x3F800000u) - 1.0f;
  return u < 0.9f;
}

// ---------------- Pass 1: per-(b,k) column max & inv-sum --------------------
// grid: 16*32 blocks (b, ktile of 64). 256 thr: lane=k_local, g=wave=q-subset.
__global__ __launch_bounds__(256) void dotatt_colstats(
    const float* __restrict__ Q, const float* __restrict__ K,
    float* __restrict__ Mcol, float* __restrict__ Rcol) {
  __shared__ float tile[64][68];      // K tile, then reused as Q tiles
  __shared__ float2 mz[4][64];

  const int bid   = blockIdx.x;
  const int b     = bid >> 5;
  const int kbase = (bid & 31) << 6;
  const int tid   = threadIdx.x;
  const int lane  = tid & 63;
  const int g     = tid >> 6;

  const float* Kb = K + ((size_t)b * LQ + kbase) * DD;
  const float* Qb = Q + (size_t)b * LQ * DD;

  // stage K tile (64x64, contiguous) as float4
  {
    const float4* src = (const float4*)Kb;
#pragma unroll
    for (int i = 0; i < 4; ++i) {
      int idx = tid + (i << 8);
      int r = idx >> 4, c4 = idx & 15;
      *(float4*)&tile[r][c4 * 4] = src[idx];
    }
  }
  __syncthreads();

  // my K row -> registers
  float kreg[64];
#pragma unroll
  for (int c4 = 0; c4 < 16; ++c4) {
    float4 v = *(const float4*)&tile[lane][c4 * 4];
    kreg[4*c4+0] = v.x; kreg[4*c4+1] = v.y; kreg[4*c4+2] = v.z; kreg[4*c4+3] = v.w;
  }
  __syncthreads();

  float m = -1e30f, z = 0.0f;

  for (int qt = 0; qt < 32; ++qt) {
    const float4* src = (const float4*)(Qb + (size_t)qt * 64 * DD);
#pragma unroll
    for (int i = 0; i < 4; ++i) {
      int idx = tid + (i << 8);
      int r = idx >> 4, c4 = idx & 15;
      *(float4*)&tile[r][c4 * 4] = src[idx];
    }
    __syncthreads();

#pragma unroll 1
    for (int i = 0; i < 16; ++i) {
      const int ql = (g << 4) + i;
      const float4* qrow = (const float4*)&tile[ql][0];  // wave-broadcast reads
      float sx = 0.f, sy = 0.f, sz = 0.f, sw = 0.f;
#pragma unroll
      for (int c4 = 0; c4 < 16; ++c4) {
        float4 qv = qrow[c4];
        sx += qv.x * kreg[4*c4+0];
        sy += qv.y * kreg[4*c4+1];
        sz += qv.z * kreg[4*c4+2];
        sw += qv.w * kreg[4*c4+3];
      }
      float s = ((sx + sy) + (sz + sw)) * 64.0f;
      // skip if negligible for every lane (term < e^-20 rel. to running max)
      if (!__all(s < m - 20.0f)) {
        float mn = fmaxf(m, s);
        z = z * __expf(m - mn) + __expf(s - mn);
        m = mn;
      }
    }
    __syncthreads();
  }

  mz[g][lane] = make_float2(m, z);
  __syncthreads();
  if (tid < 64) {
    float2 p0 = mz[0][tid], p1 = mz[1][tid], p2 = mz[2][tid], p3 = mz[3][tid];
    float M = fmaxf(fmaxf(p0.x, p1.x), fmaxf(p2.x, p3.x));
    float Z = p0.y * __expf(p0.x - M) + p1.y * __expf(p1.x - M)
            + p2.y * __expf(p2.x - M) + p3.y * __expf(p3.x - M);
    Mcol[(size_t)b * LQ + kbase + tid] = M;
    Rcol[(size_t)b * LQ + kbase + tid] = 1.0f / (0.9f * Z);
  }
}

// ---------------- Pass 2: O[q,:] = sum_k exp(s-M)*R*keep * V[k,:] -----------
// grid: 16*32 blocks (b, qtile of 64). 256 thr: lane=q_local, wave g owns
// k-quarter [g*512, g*512+512) with wave-private LDS K/V tiles (no barriers).
__global__ __launch_bounds__(256) void dotatt_out(
    const float* __restrict__ Q, const float* __restrict__ K,
    const float* __restrict__ V,
    const float* __restrict__ Mcol, const float* __restrict__ Rcol,
    float* __restrict__ Out) {
  __shared__ float qs[64][68];          // Q stage, reused for epilogue reduce
  __shared__ float kv[4][2][16][68];    // per-wave K and V tiles

  const int bid   = blockIdx.x;
  const int b     = bid >> 5;
  const int qbase = (bid & 31) << 6;
  const int tid   = threadIdx.x;
  const int lane  = tid & 63;
  const int g     = tid >> 6;

  const float* Qb = Q + ((size_t)b * LQ + qbase) * DD;

  {
    const float4* src = (const float4*)Qb;
#pragma unroll
    for (int i = 0; i < 4; ++i) {
      int idx = tid + (i << 8);
      int r = idx >> 4, c4 = idx & 15;
      *(float4*)&qs[r][c4 * 4] = src[idx];
    }
  }
  __syncthreads();

  float qreg[64];
#pragma unroll
  for (int c4 = 0; c4 < 16; ++c4) {
    float4 v = *(const float4*)&qs[lane][c4 * 4];
    qreg[4*c4+0] = v.x; qreg[4*c4+1] = v.y; qreg[4*c4+2] = v.z; qreg[4*c4+3] = v.w;
  }

  float acc[64];
#pragma unroll
  for (int d = 0; d < 64; ++d) acc[d] = 0.f;

  const float* Kb = K + (size_t)b * LQ * DD;
  const float* Vb = V + (size_t)b * LQ * DD;
  const float* Mb = Mcol + (size_t)b * LQ;
  const float* Rb = Rcol + (size_t)b * LQ;

  const uint32_t jrow = ((uint32_t)b * LQ + (uint32_t)(qbase + lane)) * (uint32_t)LQ;

#pragma unroll 1
  for (int t = 0; t < 32; ++t) {
    const int k0 = (g << 9) + (t << 4);
    // wave-local stage (wave-synchronous; buffers are wave-private)
    {
      const float4* ks = (const float4*)(Kb + (size_t)k0 * DD);
      const float4* vs = (const float4*)(Vb + (size_t)k0 * DD);
#pragma unroll
      for (int i = 0; i < 4; ++i) {
        int idx = lane + (i << 6);
        int r = idx >> 4, c4 = idx & 15;
        *(float4*)&kv[g][0][r][c4 * 4] = ks[idx];
        *(float4*)&kv[g][1][r][c4 * 4] = vs[idx];
      }
    }
    const float mreg = Mb[k0 + (lane & 15)];
    const float rreg = Rb[k0 + (lane & 15)];

#pragma unroll 1
    for (int kk = 0; kk < 16; ++kk) {
      const float Mk = __shfl(mreg, kk);
      const float4* krow = (const float4*)&kv[g][0][kk][0];
      float sx = 0.f, sy = 0.f, sz = 0.f, sw = 0.f;
#pragma unroll
      for (int c4 = 0; c4 < 16; ++c4) {
        float4 kvv = krow[c4];
        sx += kvv.x * qreg[4*c4+0];
        sy += kvv.y * qreg[4*c4+1];
        sz += kvv.z * qreg[4*c4+2];
        sw += kvv.w * qreg[4*c4+3];
      }
      float s = ((sx + sy) + (sz + sw)) * 64.0f - Mk;
      if (__all(s < -25.0f)) continue;   // all contributions < 1.5e-11
      const float Rk = __shfl(rreg, kk);
      float w = __expf(s) * Rk;
      if (!keep_bit(jrow + (uint32_t)(k0 + kk))) w = 0.f;
      const float4* vrow = (const float4*)&kv[g][1][kk][0];
#pragma unroll
      for (int c4 = 0; c4 < 16; ++c4) {
        float4 vv = vrow[c4];
        acc[4*c4+0] += w * vv.x;
        acc[4*c4+1] += w * vv.y;
        acc[4*c4+2] += w * vv.z;
        acc[4*c4+3] += w * vv.w;
      }
    }
  }

  __syncthreads();
  // reduce 4 wave-partials into qs
  for (int gg = 0; gg < 4; ++gg) {
    if (g == gg) {
      if (gg == 0) {
#pragma unroll
        for (int d = 0; d < 64; ++d) qs[lane][d] = acc[d];
      } else {
#pragma unroll
        for (int d = 0; d < 64; ++d) qs[lane][d] += acc[d];
      }
    }
    __syncthreads();
  }

  float* Ob = Out + ((size_t)b * LQ + qbase) * DD;
#pragma unroll
  for (int i = 0; i < 4; ++i) {
    int idx = tid + (i << 8);
    int r = idx >> 4, c4 = idx & 15;
    ((float4*)Ob)[idx] = *(const float4*)&qs[r][c4 * 4];
  }
}

extern "C" void kernel_launch(void* const* d_in, const int* in_sizes, int n_in,
                              void* d_out, int out_size, void* d_ws, size_t ws_size,
                              hipStream_t stream) {
  const float* Q = (const float*)d_in[0];
  const float* K = (const float*)d_in[1];
  const float* V = (const float*)d_in[2];
  float* Out  = (float*)d_out;
  float* Mcol = (float*)d_ws;                      // 16*2048 f32
  float* Rcol = Mcol + (size_t)16 * LQ;            // 16*2048 f32 (256 KB total)

  hipLaunchKernelGGL(dotatt_colstats, dim3(16 * 32), dim3(256), 0, stream,
                     Q, K, Mcol, Rcol);
  hipLaunchKernelGGL(dotatt_out, dim3(16 * 32), dim3(256), 0, stream,
                     Q, K, V, Mcol, Rcol, Out);
}

// Round 11
// 205.972 us; speedup vs baseline: 3.0297x; 3.0297x over previous
//
#include <hip/hip_runtime.h>
#include <stdint.h>

// DotAtt: B=16, Lq=Lk=2048, D=64. scores = 64*Q.K^T ; softmax over q (axis=-2);
// JAX threefry dropout p=0.1 (key 42, partitionable, bits = x0^x1); out = W.V
// Pass 1: column stats M[k], R[k]=1/(0.9*Z[k]) via split-bf16 MFMA scores.
// Pass 2: O = (exp(s-M)*R*keep) . V, same MFMA chain (bitwise-identical s).

#define LQ 2048
#define DD 64

typedef short bf16x8 __attribute__((ext_vector_type(8)));
typedef float f32x4 __attribute__((ext_vector_type(4)));
typedef unsigned short ushort_t;

#define MFMA16(a, b, c) __builtin_amdgcn_mfma_f32_16x16x32_bf16(a, b, c, 0, 0, 0)

__device__ __forceinline__ ushort_t f2bf(float x) {
  uint32_t u = __float_as_uint(x);
  return (ushort_t)((u + 0x7FFFu + ((u >> 16) & 1u)) >> 16);  // RNE
}
__device__ __forceinline__ float bf2f(ushort_t h) {
  return __uint_as_float(((uint32_t)h) << 16);
}

__device__ __forceinline__ void split8v(float4 a, float4 b, bf16x8* H, bf16x8* L) {
  float xs[8] = {a.x, a.y, a.z, a.w, b.x, b.y, b.z, b.w};
  bf16x8 h, l;
#pragma unroll
  for (int e = 0; e < 8; ++e) {
    ushort_t hh = f2bf(xs[e]);
    h[e] = (short)hh;
    l[e] = (short)f2bf(xs[e] - bf2f(hh));
  }
  *H = h; *L = l;
}

// 16x16 score tile, K-dim 64 as 2 halves, 3 split terms. SAME order in both
// passes so s is bitwise identical (M consistency).
__device__ __forceinline__ f32x4 score6(bf16x8 Ah0, bf16x8 Ah1, bf16x8 Al0, bf16x8 Al1,
                                        bf16x8 Bh0, bf16x8 Bh1, bf16x8 Bl0, bf16x8 Bl1) {
  f32x4 acc = {0.f, 0.f, 0.f, 0.f};
  acc = MFMA16(Ah0, Bh0, acc);
  acc = MFMA16(Ah1, Bh1, acc);
  acc = MFMA16(Al0, Bh0, acc);
  acc = MFMA16(Al1, Bh1, acc);
  acc = MFMA16(Ah0, Bl0, acc);
  acc = MFMA16(Ah1, Bl1, acc);
  return acc;
}

// stage one 64x64 f32 tile -> bf16 hi/lo LDS tiles (rows padded to 72)
__device__ __forceinline__ void stage_q(const float* __restrict__ gsrc,
                                        short (*Qh)[72], short (*Ql)[72], int tid) {
  const float4* src = (const float4*)gsrc;
#pragma unroll
  for (int i = 0; i < 4; ++i) {
    int idx = tid + (i << 8);
    int r = idx >> 4, c4 = idx & 15;
    float4 v = src[idx];
    short4 h, l;
    ushort_t t;
    t = f2bf(v.x); h.x = (short)t; l.x = (short)f2bf(v.x - bf2f(t));
    t = f2bf(v.y); h.y = (short)t; l.y = (short)f2bf(v.y - bf2f(t));
    t = f2bf(v.z); h.z = (short)t; l.z = (short)f2bf(v.z - bf2f(t));
    t = f2bf(v.w); h.w = (short)t; l.w = (short)f2bf(v.w - bf2f(t));
    *(short4*)&Qh[r][c4 * 4] = h;
    *(short4*)&Ql[r][c4 * 4] = l;
  }
}

__device__ __forceinline__ void tf_round(uint32_t& x0, uint32_t& x1, const int r) {
  x0 += x1;
  x1 = (x1 << r) | (x1 >> (32 - r));
  x1 ^= x0;
}

// JAX threefry2x32 partitionable draw: bits = x0^x1, key=(0,42), ctr=(0,j). Verified r9.
__device__ __forceinline__ bool keep_bit(uint32_t j) {
  const uint32_t ks1 = 42u, ks2 = 0x1BD11BDAu ^ 42u;
  uint32_t x0 = 0u;
  uint32_t x1 = j + ks1;
  tf_round(x0,x1,13); tf_round(x0,x1,15); tf_round(x0,x1,26); tf_round(x0,x1,6);
  x0 += ks1; x1 += ks2 + 1u;
  tf_round(x0,x1,17); tf_round(x0,x1,29); tf_round(x0,x1,16); tf_round(x0,x1,24);
  x0 += ks2; x1 += 0u + 2u;
  tf_round(x0,x1,13); tf_round(x0,x1,15); tf_round(x0,x1,26); tf_round(x0,x1,6);
  x0 += 0u; x1 += ks1 + 3u;
  tf_round(x0,x1,17); tf_round(x0,x1,29); tf_round(x0,x1,16); tf_round(x0,x1,24);
  x0 += ks1; x1 += ks2 + 4u;
  tf_round(x0,x1,13); tf_round(x0,x1,15); tf_round(x0,x1,26); tf_round(x0,x1,6);
  x0 += ks2; x1 += 0u + 5u;
  uint32_t bits = x0 ^ x1;
  float u = __uint_as_float((bits >> 9) | 0x3F800000u) - 1.0f;
  return u < 0.9f;
}

// ---------------- Pass 1: per-(b,k) column max & inv-sum (MFMA) -------------
// 512 blocks (b, ktile64), 256 thr. Wave g owns 16 k-cols; B-frags in regs.
__global__ __launch_bounds__(256) void dotatt_colstats(
    const float* __restrict__ Q, const float* __restrict__ K,
    float* __restrict__ Mcol, float* __restrict__ Rcol) {
  __shared__ short Qh[64][72];
  __shared__ short Ql[64][72];
  const int bid = blockIdx.x;
  const int b = bid >> 5;
  const int kbase = (bid & 31) << 6;
  const int tid = threadIdx.x;
  const int lane = tid & 63;
  const int g = tid >> 6;
  const int kr = lane & 15;
  const int d0 = (lane >> 4) << 3;

  // B-frags: K row (kbase+16g+kr), d0..d0+7 and d0+32.. ; each row used once/wave -> no LDS
  bf16x8 Bh0, Bl0, Bh1, Bl1;
  {
    const float* kp = K + ((size_t)b * LQ + kbase + (g << 4) + kr) * DD + d0;
    float4 a0 = *(const float4*)kp;
    float4 a1 = *(const float4*)(kp + 4);
    float4 a2 = *(const float4*)(kp + 32);
    float4 a3 = *(const float4*)(kp + 36);
    split8v(a0, a1, &Bh0, &Bl0);
    split8v(a2, a3, &Bh1, &Bl1);
  }

  const float* Qb = Q + (size_t)b * LQ * DD;
  float m = -1e30f, z = 0.f;

#pragma unroll 1
  for (int qt = 0; qt < 32; ++qt) {
    stage_q(Qb + (size_t)qt * 64 * DD, Qh, Ql, tid);
    __syncthreads();
    float s16[16];
#pragma unroll
    for (int qtile = 0; qtile < 4; ++qtile) {
      const int row = (qtile << 4) + kr;
      bf16x8 Ah0 = *(const bf16x8*)&Qh[row][d0];
      bf16x8 Ah1 = *(const bf16x8*)&Qh[row][d0 + 32];
      bf16x8 Al0 = *(const bf16x8*)&Ql[row][d0];
      bf16x8 Al1 = *(const bf16x8*)&Ql[row][d0 + 32];
      f32x4 s = score6(Ah0, Ah1, Al0, Al1, Bh0, Bh1, Bl0, Bl1);
#pragma unroll
      for (int r = 0; r < 4; ++r) s16[(qtile << 2) + r] = s[r] * 64.f;
    }
    __syncthreads();
    float mx = s16[0];
#pragma unroll
    for (int i = 1; i < 16; ++i) mx = fmaxf(mx, s16[i]);
    if (!__all(mx < m - 20.f)) {
      float mn = fmaxf(m, mx);
      float zz = 0.f;
#pragma unroll
      for (int i = 0; i < 16; ++i) zz += __expf(s16[i] - mn);
      z = z * __expf(m - mn) + zz;
      m = mn;
    }
  }
  // merge 4 lane-groups (same col, disjoint q subsets)
#pragma unroll
  for (int off = 16; off < 64; off <<= 1) {
    float om = __shfl_xor(m, off);
    float oz = __shfl_xor(z, off);
    float mn = fmaxf(m, om);
    z = z * __expf(m - mn) + oz * __expf(om - mn);
    m = mn;
  }
  if (lane < 16) {
    size_t o = (size_t)b * LQ + kbase + (g << 4) + lane;
    Mcol[o] = m;
    Rcol[o] = 1.0f / (0.9f * z);
  }
}

// ---------------- Pass 2: O[q,:] = sum_k exp(s-M)*R*keep * V[k,:] -----------
// 512 blocks (b, qtile64), 256 thr. Wave g owns k-quarter; MFMA scores ->
// wave-private LDS bounce -> lane=q scan with skip + broadcast-V PV.
__global__ __launch_bounds__(256) void dotatt_out(
    const float* __restrict__ Q, const float* __restrict__ K,
    const float* __restrict__ V,
    const float* __restrict__ Mcol, const float* __restrict__ Rcol,
    float* __restrict__ Out) {
  __shared__ short Qh[64][72];
  __shared__ short Ql[64][72];
  __shared__ float Slds[4][64][17];   // wave-private S tiles; reused in epilogue

  const int bid = blockIdx.x;
  const int b = bid >> 5;
  const int qbase = (bid & 31) << 6;
  const int tid = threadIdx.x;
  const int lane = tid & 63;
  const int g = tid >> 6;
  const int kr = lane & 15;
  const int d0 = (lane >> 4) << 3;

  stage_q(Q + ((size_t)b * LQ + qbase) * DD, Qh, Ql, tid);
  __syncthreads();

  float acc[64];
#pragma unroll
  for (int d = 0; d < 64; ++d) acc[d] = 0.f;

  const float* Kb = K + (size_t)b * LQ * DD;
  const float* Vb = V + (size_t)b * LQ * DD;
  const float* Mb = Mcol + (size_t)b * LQ;
  const float* Rb = Rcol + (size_t)b * LQ;
  const uint32_t jrow = ((uint32_t)b * LQ + (uint32_t)(qbase + lane)) * (uint32_t)LQ;

#pragma unroll 1
  for (int t = 0; t < 32; ++t) {
    const int k0 = (g << 9) + (t << 4);
    // B-frags direct from global (each K row used once per wave)
    bf16x8 Bh0, Bl0, Bh1, Bl1;
    {
      const float* kp = Kb + (size_t)(k0 + kr) * DD + d0;
      float4 a0 = *(const float4*)kp;
      float4 a1 = *(const float4*)(kp + 4);
      float4 a2 = *(const float4*)(kp + 32);
      float4 a3 = *(const float4*)(kp + 36);
      split8v(a0, a1, &Bh0, &Bl0);
      split8v(a2, a3, &Bh1, &Bl1);
    }
    const float Mw = Mb[k0 + kr];
    const float rr = Rb[k0 + kr];

    float sm[16];
#pragma unroll
    for (int qtile = 0; qtile < 4; ++qtile) {
      const int row = (qtile << 4) + kr;
      bf16x8 Ah0 = *(const bf16x8*)&Qh[row][d0];
      bf16x8 Ah1 = *(const bf16x8*)&Qh[row][d0 + 32];
      bf16x8 Al0 = *(const bf16x8*)&Ql[row][d0];
      bf16x8 Al1 = *(const bf16x8*)&Ql[row][d0 + 32];
      f32x4 s = score6(Ah0, Ah1, Al0, Al1, Bh0, Bh1, Bl0, Bl1);
#pragma unroll
      for (int r = 0; r < 4; ++r) sm[(qtile << 2) + r] = s[r] * 64.f - Mw;
    }
    float mx = sm[0];
#pragma unroll
    for (int i = 1; i < 16; ++i) mx = fmaxf(mx, sm[i]);
    if (__all(mx < -25.f)) continue;          // whole 64q x 16k chunk negligible

    // bounce S to wave-private LDS (lane holds col kr, rows (lane>>4)*4+r)
#pragma unroll
    for (int qtile = 0; qtile < 4; ++qtile)
#pragma unroll
      for (int r = 0; r < 4; ++r)
        Slds[g][(qtile << 4) + ((lane >> 4) << 2) + r][kr] = sm[(qtile << 2) + r];

#pragma unroll 1
    for (int kk = 0; kk < 16; ++kk) {
      float smv = Slds[g][lane][kk];          // lane = q row
      if (__all(smv < -25.f)) continue;
      float Rk = __shfl(rr, kk);
      float w = __expf(smv) * Rk;
      if (!keep_bit(jrow + (uint32_t)(k0 + kk))) w = 0.f;
      const float4* vrow = (const float4*)(Vb + (size_t)(k0 + kk) * DD);  // uniform broadcast
#pragma unroll
      for (int c4 = 0; c4 < 16; ++c4) {
        float4 vv = vrow[c4];
        acc[4 * c4 + 0] += w * vv.x;
        acc[4 * c4 + 1] += w * vv.y;
        acc[4 * c4 + 2] += w * vv.z;
        acc[4 * c4 + 3] += w * vv.w;
      }
    }
  }

  __syncthreads();
  // reduce 4 wave-partials (reuse Slds: 4*64*17 = 64*68 floats)
  float (*qs)[68] = (float(*)[68])&Slds[0][0][0];
  for (int gg = 0; gg < 4; ++gg) {
    if (g == gg) {
      if (gg == 0) {
#pragma unroll
        for (int d = 0; d < 64; ++d) qs[lane][d] = acc[d];
      } else {
#pragma unroll
        for (int d = 0; d < 64; ++d) qs[lane][d] += acc[d];
      }
    }
    __syncthreads();
  }

  float* Ob = Out + ((size_t)b * LQ + qbase) * DD;
#pragma unroll
  for (int i = 0; i < 4; ++i) {
    int idx = tid + (i << 8);
    int r = idx >> 4, c4 = idx & 15;
    ((float4*)Ob)[idx] = *(const float4*)&qs[r][c4 * 4];
  }
}

extern "C" void kernel_launch(void* const* d_in, const int* in_sizes, int n_in,
                              void* d_out, int out_size, void* d_ws, size_t ws_size,
                              hipStream_t stream) {
  const float* Q = (const float*)d_in[0];
  const float* K = (const float*)d_in[1];
  const float* V = (const float*)d_in[2];
  float* Out  = (float*)d_out;
  float* Mcol = (float*)d_ws;                      // 16*2048 f32
  float* Rcol = Mcol + (size_t)16 * LQ;            // 16*2048 f32 (256 KB total)

  hipLaunchKernelGGL(dotatt_colstats, dim3(16 * 32), dim3(256), 0, stream,
                     Q, K, Mcol, Rcol);
  hipLaunchKernelGGL(dotatt_out, dim3(16 * 32), dim3(256), 0, stream,
                     Q, K, V, Mcol, Rcol, Out);
}